// Round 14
// baseline (628.899 us; speedup 1.0000x reference)
//
#include <hip/hip_runtime.h>
#include <hip/hip_cooperative_groups.h>
#include <stdint.h>
#include <stddef.h>

namespace cg = cooperative_groups;

// ---------------- problem constants ----------------
#define BATCH 8
#define NPT   2048
#define NB    (BATCH*NPT)            // 16384
#define CAP   128                    // max sparse entries per row/col
#define ITERS 100
#define TPB   1024
#define NWAVE (TPB/64)
#define C50      1.9287498479639178e-22f   // expf(-50.f) == clamp floor of K
#define MUV      (1.0f/2048.0f)
#define EPS_DIVF 1e-8f
// Sparsity radius: d^2 < 0.1089 (d < 0.33). See r8/r9 analysis: dropped shell
// sums stay below the EPS_DIV clamp floor for isolated rows. The sparse
// epilogue drops far-pair transport mass bounded by ~2e-8 absolute.
#define R2THR 0.1089f

// ---------------- workspace layout (bytes), 16B-aligned ----------------
#define OFF_GMAX 0u                                   // gmax[dir][b*32+g], 2 KB used
#define OFF_CNT  4096u                                // u16 cnt0[b][n], 32 KB used
#define OFF_PERM (OFF_CNT  + (size_t)2*NB*2)          // u16 perm[dir][b][p], 64 KB (pos -> orig)
#define OFF_IPRM (OFF_PERM + (size_t)2*NB*2)          // u16 inv [dir][b][n], 64 KB (orig -> pos)
#define OFF_SPTS (OFF_IPRM + (size_t)2*NB*2)          // float4, 256 KB
#define OFF_TPTS (OFF_SPTS + (size_t)NB*16)
#define OFF_U    (OFF_TPTS + (size_t)NB*16)           // u32 colE offset counters (build)
#define OFF_V    (OFF_U + (size_t)NB*4)               // u32 cnt1[b][m] (count phase atomics)
#define OFF_ROWE (OFF_V + (size_t)NB*4)               // ELL-T4 slab (sorted rows), 8 MB
#define OFF_COLE (OFF_ROWE + (size_t)NB*CAP*4)        // 8 MB
// total 17,633,280 B — identical to the passing layout

// Entry format: value bits [31:14] (truncated; idx garbage adds zero-mean
// [0,2^-9) back), idx bits [13:2] = pre-shifted region-relative cell index.
// Gather address = single AND 0x3FFC; region base (U=0 / V=16384) folds into
// the ds_read offset immediate via phase-duplicated scan code.
__device__ __forceinline__ uint32_t pack_entry(float kv, int idx) {
    return (__float_as_uint(kv) & 0xFFFFC000u) | ((uint32_t)idx << 2);
}

// copy1 position map: bank (pi&31) mixes mid bits of i into the bank bits.
__device__ __forceinline__ uint32_t pi_map(uint32_t i) {
    return (i & 0x7E0u) | ((i ^ (i >> 5)) & 31u);
}

// ELL-T4 address of entry `ofs` of sorted-row `p` within a batch slab (dword units)
__device__ __forceinline__ size_t ellt4_addr(int ofs, int p) {
    return (size_t)(ofs >> 2) * (NPT*4) + (size_t)p * 4 + (ofs & 3);
}

__device__ __forceinline__ uint4 ldE(const uint32_t* ep, int j4) {
    return *(const uint4*)(ep + (size_t)j4 * (NPT*4));   // coalesced 1KB per (group, j4)
}

// Gather: byte offset = (e & 0x3FFC); region base OFS is a compile-time const.
#define GATHER(e, OFS) (*(const float*)((const uint8_t*)W + (OFS) + ((e) & 0x3FFCu)))
#define FMA4C(a0, a1, a2, a3, e4, OFS) do { \
    a0 = fmaf(__uint_as_float((e4).x), GATHER((e4).x, OFS), a0); \
    a1 = fmaf(__uint_as_float((e4).y), GATHER((e4).y, OFS), a1); \
    a2 = fmaf(__uint_as_float((e4).z), GATHER((e4).z, OFS), a2); \
    a3 = fmaf(__uint_as_float((e4).w), GATHER((e4).w, OFS), a3); \
} while (0)

#define SCAN(OFS) do { \
    FMA4C(A0,A1,A2,A3, pfA0, OFS); FMA4C(A0,A1,A2,A3, pfA1, OFS); \
    FMA4C(B0,B1,B2,B3, pfB0, OFS); FMA4C(B0,B1,B2,B3, pfB1, OFS); \
    int j4 = 2; \
    for (; j4 + 1 < jmin; j4 += 2) { \
        uint4 x0 = ldE(eA, j4),   y0 = ldE(eB, j4); \
        uint4 x1 = ldE(eA, j4+1), y1 = ldE(eB, j4+1); \
        FMA4C(A0,A1,A2,A3, x0, OFS); FMA4C(B0,B1,B2,B3, y0, OFS); \
        FMA4C(A0,A1,A2,A3, x1, OFS); FMA4C(B0,B1,B2,B3, y1, OFS); \
    } \
    if (j4 < jmin) { \
        uint4 x0 = ldE(eA, j4), y0 = ldE(eB, j4); \
        FMA4C(A0,A1,A2,A3, x0, OFS); FMA4C(B0,B1,B2,B3, y0, OFS); \
        ++j4; \
    } \
    for (; j4 + 1 < jbig; j4 += 2) { \
        uint4 x0 = ldE(eL, j4), x1 = ldE(eL, j4+1); \
        FMA4C(R0,R1,R2,R3, x0, OFS); FMA4C(R4,R5,R6,R7, x1, OFS); \
    } \
    if (j4 < jbig) { uint4 x0 = ldE(eL, j4); FMA4C(R0,R1,R2,R3, x0, OFS); } \
} while (0)

// LDS overlay: one phase live at a time (phases separated by grid/block syncs)
union ShMem {
    struct { float4 opts[NPT]; uint16_t rows[64]; uint16_t invp[NPT]; } bc;   // count/build
    struct { uint32_t hist[CAP+2]; uint32_t bofs[CAP+2]; uint16_t permL[NPT]; } s; // sort
    struct { uint32_t se[32*256]; uint8_t cw[128*32]; } f;                     // sched
    struct { float W[8192]; float4 red[2][NWAVE/4]; uint32_t gmL[2][32]; } d;  // iterate
};

extern "C" __global__ __launch_bounds__(TPB, 1)
void emd_fused_56831007261025(const float* __restrict__ src,
                              const float* __restrict__ tgt,
                              uint8_t* __restrict__ wsb,
                              float* __restrict__ out)
{
    __shared__ ShMem sh;
    cg::grid_group grid = cg::this_grid();

    const int tid  = threadIdx.x;
    const int lane = tid & 63;
    const int wid  = tid >> 6;
    const int bid  = blockIdx.x;

    uint16_t* cnt0g = (uint16_t*)(wsb + OFF_CNT);
    uint32_t* cnt1g = (uint32_t*)(wsb + OFF_V);
    uint32_t* scr1g = (uint32_t*)(wsb + OFF_U);
    float4*   gspts = (float4*)  (wsb + OFF_SPTS);
    float4*   gtpts = (float4*)  (wsb + OFF_TPTS);
    uint32_t* rowEg = (uint32_t*)(wsb + OFF_ROWE);
    uint32_t* colEg = (uint32_t*)(wsb + OFF_COLE);
    uint32_t* gmaxg = (uint32_t*)(wsb + OFF_GMAX);

    // ================= P0: zero atomic counters (cross-block targets) =========
    if (bid == 0 && tid == 0) *out = 0.0f;
    if (tid < 64) {
        cnt1g[(size_t)bid*64 + tid] = 0u;
        scr1g[(size_t)bid*64 + tid] = 0u;
    }
    grid.sync();

    // ================= P1: stage points + zero slabs + symmetric dense count ==
    {
        const int b = bid >> 5, g = bid & 31;
        const size_t base  = (size_t)b * NPT;
        const size_t ebase = (size_t)b * NPT * CAP;

        if (tid < 64) {
            size_t gi = base + g*64 + tid;
            gspts[gi] = make_float4(src[3*gi], src[3*gi+1], src[3*gi+2], 0.0f);
            gtpts[gi] = make_float4(tgt[3*gi], tgt[3*gi+1], tgt[3*gi+2], 0.0f);
        }
        // zero this block's (b,g) slice of both slabs (pad slots must read 0)
        for (int idx = tid; idx < 32*256; idx += TPB) {
            int j4 = idx >> 8, t = idx & 255;
            size_t a = ebase + (size_t)j4*(NPT*4) + (size_t)g*256 + t;
            rowEg[a] = 0u;
            colEg[a] = 0u;
        }
        for (int i = tid; i < NPT; i += TPB) {
            size_t gi = base + i;
            sh.bc.opts[i] = make_float4(tgt[3*gi], tgt[3*gi+1], tgt[3*gi+2], 0.0f);
        }
        __syncthreads();

        // ONE dense pass: cnt0 rows via ballot; cnt1 cols via atomics (bit-exact
        // symmetric: d2 identical both directions).
        for (int r = 0; r < 4; ++r) {
            int n = g*64 + wid*4 + r;
            size_t gi = base + n;
            float4 sp = make_float4(src[3*gi], src[3*gi+1], src[3*gi+2], 0.0f);
            uint32_t c = 0;
            for (int mb = 0; mb < NPT; mb += 64) {
                int m = mb + lane;
                float4 tp = sh.bc.opts[m];
                float dx = sp.x - tp.x, dy = sp.y - tp.y, dz = sp.z - tp.z;
                float d2 = dx*dx + dy*dy + dz*dz;
                bool p = d2 < R2THR;
                if (p) atomicAdd(&cnt1g[base + m], 1u);
                c += (uint32_t)__popcll(__ballot(p));
            }
            if (lane == 0) cnt0g[gi] = (uint16_t)((c < CAP) ? c : CAP);
        }
    }
    grid.sync();

    // ================= P2: counting-sort rows per (dir, batch), 16 blocks =====
    if (bid < 16) {
        const int dir = bid >> 3, b = bid & 7;
        const size_t base = (size_t)b * NPT;
        uint16_t* perm = (uint16_t*)(wsb + OFF_PERM) + (size_t)dir*NB + base;
        uint16_t* inv  = (uint16_t*)(wsb + OFF_IPRM) + (size_t)dir*NB + base;
        uint32_t* gmax = gmaxg + (size_t)dir*256 + (size_t)b*32;

        for (int i = tid; i < CAP+2; i += TPB) sh.s.hist[i] = 0;
        __syncthreads();
        for (int n = tid; n < NPT; n += TPB) {
            uint32_t cv = dir ? cnt1g[base + n] : (uint32_t)cnt0g[base + n];
            if (cv > CAP) cv = CAP;
            atomicAdd(&sh.s.hist[cv], 1u);
        }
        __syncthreads();
        if (tid == 0) {
            uint32_t run = 0;
            for (int i = 0; i < CAP+2; ++i) { sh.s.bofs[i] = run; run += sh.s.hist[i]; }
        }
        __syncthreads();
        for (int n = tid; n < NPT; n += TPB) {
            uint32_t cv = dir ? cnt1g[base + n] : (uint32_t)cnt0g[base + n];
            if (cv > CAP) cv = CAP;
            uint32_t p = atomicAdd(&sh.s.bofs[cv], 1u);
            sh.s.permL[p] = (uint16_t)n;
        }
        __syncthreads();
        for (int p = tid; p < NPT; p += TPB) {
            uint16_t o = sh.s.permL[p];
            perm[p] = o;
            inv[o]  = (uint16_t)p;
        }
        if (tid < 32) {
            uint16_t o = sh.s.permL[tid*64 + 63];
            uint32_t cv = dir ? cnt1g[base + o] : (uint32_t)cnt0g[base + o];
            if (cv > CAP) cv = CAP;
            gmax[tid] = cv;                      // sorted ascending -> group max
        }
    }
    grid.sync();

    // ================= P3: ONE symmetric dense pass builds BOTH slabs =========
    {
        const int b = bid >> 5, g = bid & 31;
        const size_t base  = (size_t)b * NPT;
        const size_t ebase = (size_t)b * NPT * CAP;
        uint32_t* scr1 = scr1g + base;
        const uint16_t* permG = (const uint16_t*)(wsb + OFF_PERM) + base;              // dir0
        const uint16_t* invG  = (const uint16_t*)(wsb + OFF_IPRM) + (size_t)NB + base; // dir1

        for (int i = tid; i < NPT; i += TPB) {
            sh.bc.opts[i] = gtpts[base + i];
            sh.bc.invp[i] = invG[i];
        }
        if (tid < 64) sh.bc.rows[tid] = permG[g*64 + tid];
        __syncthreads();

        for (int r = 0; r < 4; ++r) {
            int psort = g*64 + wid*4 + r;              // dir0 sorted position
            int n     = sh.bc.rows[wid*4 + r];         // original src row
            float4 sp = gspts[base + n];
            uint32_t c = 0;
            for (int mb = 0; mb < NPT; mb += 64) {
                int m = mb + lane;
                float4 tp = sh.bc.opts[m];
                float dx = sp.x - tp.x, dy = sp.y - tp.y, dz = sp.z - tp.z;
                float d2 = dx*dx + dy*dy + dz*dz;
                bool p = d2 < R2THR;
                uint64_t mask = __ballot(p);
                if (p) {
                    float d  = sqrtf(d2);
                    float kv = expf(-100.0f * d) - C50;
                    uint32_t ofs = c + (uint32_t)__popcll(mask & ((1ull << lane) - 1ull));
                    if (ofs < CAP)
                        rowEg[ebase + ellt4_addr((int)ofs, psort)] = pack_entry(kv, sh.bc.invp[m]);
                    uint32_t q  = sh.bc.invp[m];               // dir1 sorted row
                    uint32_t oj = atomicAdd(&scr1[m], 1u);
                    if (oj < CAP)
                        colEg[ebase + ellt4_addr((int)oj, (int)q)] = pack_entry(kv, psort);
                }
                c += (uint32_t)__popcll(mask);
            }
        }
    }
    grid.sync();

    // ================= P4: two-choice bank scheduler (2 tasks/block) ==========
    for (int tk = 0; tk < 2; ++tk) {
        const int blk = bid*2 + tk;          // 512 tasks: dir | b | g
        const int g   = blk & 31;
        const int b   = (blk >> 5) & 7;
        const int dir = blk >> 8;
        const size_t ebase = (size_t)b * NPT * CAP;
        uint32_t* E = (dir ? colEg : rowEg) + ebase;
        const uint32_t* gmax = gmaxg + (size_t)dir*256 + (size_t)b*32;

        const int cm4 = ((int)gmax[g] + 3) >> 2;
        const int S   = cm4 * 4;

        __syncthreads();   // protect sh.f reuse across tasks / phases
        for (int u = tid; u < cm4*64; u += TPB) {
            int j4 = u >> 6, t = u & 63;
            *(uint4*)&sh.f.se[j4*256 + t*4] =
                *(const uint4*)(E + (size_t)j4*(NPT*4) + (size_t)g*256 + (size_t)t*4);
        }
        __syncthreads();

        for (int s0 = tid; s0 < S; s0 += TPB) {        // S <= 128 => tid < 128 active
            *(uint64_t*)(sh.f.cw + s0*32 +  0) = 0ull;
            *(uint64_t*)(sh.f.cw + s0*32 +  8) = 0ull;
            *(uint64_t*)(sh.f.cw + s0*32 + 16) = 0ull;
            *(uint64_t*)(sh.f.cw + s0*32 + 24) = 0ull;

            const int base = (s0 >> 2)*256 + (s0 & 3);
            uint64_t padmask = 0ull;
            for (int t = 0; t < 64; ++t) {
                uint32_t e = sh.f.se[base + t*4];
                if ((e >> 14) == 0u) { padmask |= 1ull << t; continue; }
                uint32_t i  = (e >> 2) & 0x7FFu;
                uint32_t p1 = pi_map(i);
                uint32_t b0 = i & 31u, b1 = p1 & 31u;
                uint8_t  c0 = sh.f.cw[s0*32 + b0], c1 = sh.f.cw[s0*32 + b1];
                uint32_t idx;
                if (c1 < c0) { idx = 2048u + p1; sh.f.cw[s0*32 + b1] = (uint8_t)(c1 + 1); }
                else         { idx = i;          sh.f.cw[s0*32 + b0] = (uint8_t)(c0 + 1); }
                sh.f.se[base + t*4] = (e & 0xFFFFC000u) | (idx << 2);
            }
            if (padmask) {
                uint32_t best = 0, bc = 255;
                for (uint32_t bb = 0; bb < 32; ++bb) {
                    uint32_t c = sh.f.cw[s0*32 + bb];
                    if (c < bc) { bc = c; best = bb; }
                }
                uint32_t pw = (2048u + best) << 2;  // value bits zero -> pad, skipped later
                while (padmask) {
                    int t = __ffsll((unsigned long long)padmask) - 1;
                    padmask &= padmask - 1;
                    sh.f.se[base + t*4] = pw;
                }
            }
        }
        __syncthreads();

        for (int u = tid; u < cm4*64; u += TPB) {
            int j4 = u >> 6, t = u & 63;
            *(uint4*)(E + (size_t)j4*(NPT*4) + (size_t)g*256 + (size_t)t*4) =
                *(const uint4*)&sh.f.se[j4*256 + t*4];
        }
    }
    grid.sync();

    // ================= P5: 100 Sinkhorn iterations + fused sparse epilogue ====
    if (bid >= BATCH) return;                 // no further grid syncs occur
    {
        const int b = bid;
        const size_t ebase = (size_t)b * NPT * CAP;
        const uint32_t* rowE = rowEg + ebase;
        const uint32_t* colE = colEg + ebase;
        float* const W = sh.d.W;

        if (tid < 32) {
            sh.d.gmL[0][tid] = gmaxg[(size_t)b*32 + tid];
            sh.d.gmL[1][tid] = gmaxg[256 + (size_t)b*32 + tid];
        }
        for (int i = tid; i < 4096; i += TPB) W[4096 + i] = 1.0f;  // v0 = ones (both copies)
        __syncthreads();

        const int gA = wid, gB = 31 - wid;
        const int posA = gA*64 + lane, posB = gB*64 + lane;
        const int pA1 = 2048 + (int)pi_map((uint32_t)posA);
        const int pB1 = 2048 + (int)pi_map((uint32_t)posB);
        const int jAu = (__builtin_amdgcn_readfirstlane((int)sh.d.gmL[0][gA]) + 3) >> 2;
        const int jBu = (__builtin_amdgcn_readfirstlane((int)sh.d.gmL[0][gB]) + 3) >> 2;
        const int jAv = (__builtin_amdgcn_readfirstlane((int)sh.d.gmL[1][gA]) + 3) >> 2;
        const int jBv = (__builtin_amdgcn_readfirstlane((int)sh.d.gmL[1][gB]) + 3) >> 2;
        const uint32_t* rA = rowE + (size_t)posA * 4;
        const uint32_t* rB = rowE + (size_t)posB * 4;
        const uint32_t* cA = colE + (size_t)posA * 4;
        const uint32_t* cB = colE + (size_t)posB * 4;

        uint4 pfA0 = ldE(rA, 0), pfA1 = ldE(rA, 1);
        uint4 pfB0 = ldE(rB, 0), pfB1 = ldE(rB, 1);

        for (int ph = 0; ph < 2*ITERS; ++ph) {
            const bool up = (ph & 1) == 0;               // u-phase reads V region, writes U
            const int jA = up ? jAu : jAv;
            const int jB = up ? jBu : jBv;
            const uint32_t* eA = up ? rA : cA;
            const uint32_t* eB = up ? rB : cB;
            const uint32_t* eL = (jA > jB) ? eA : eB;    // wave-uniform
            const int jmin = (jA < jB) ? jA : jB;
            const int jbig = (jA > jB) ? jA : jB;

            float A0=0.f,A1=0.f,A2=0.f,A3=0.f, B0=0.f,B1=0.f,B2=0.f,B3=0.f;
            float R0=0.f,R1=0.f,R2=0.f,R3=0.f, R4=0.f,R5=0.f,R6=0.f,R7=0.f;

            if (up) SCAN(16384); else SCAN(0);

            float accA = (A0+A1)+(A2+A3);
            float accB = (B0+B1)+(B2+B3);
            float accR = ((R0+R1)+(R2+R3)) + ((R4+R5)+(R6+R7));
            if (jA > jB) accA += accR; else accB += accR;

            const uint32_t* nA = up ? cA : rA;
            const uint32_t* nB = up ? cB : rB;
            pfA0 = ldE(nA, 0); pfA1 = ldE(nA, 1);
            pfB0 = ldE(nB, 0); pfB1 = ldE(nB, 1);

            float Sw;
            if (ph == 0) {
                Sw = (float)NPT;                         // sum(v0) = 2048 exactly
            } else {
                const float4* rp = sh.d.red[(ph - 1) & 1];
                float4 r0 = rp[0], r1 = rp[1], r2 = rp[2], r3 = rp[3];
                Sw = (((r0.x+r0.y)+(r0.z+r0.w)) + ((r1.x+r1.y)+(r1.z+r1.w)))
                   + (((r2.x+r2.y)+(r2.z+r2.w)) + ((r3.x+r3.y)+(r3.z+r3.w)));
            }

            const int wrofs = up ? 0 : 4096;
            float valA = MUV * __builtin_amdgcn_rcpf(fmaxf(fmaf(C50, Sw, accA), EPS_DIVF));
            float valB = MUV * __builtin_amdgcn_rcpf(fmaxf(fmaf(C50, Sw, accB), EPS_DIVF));
            W[wrofs + posA] = valA;   W[wrofs + pA1] = valA;
            W[wrofs + posB] = valB;   W[wrofs + pB1] = valB;

            float psum = valA + valB;
            #pragma unroll
            for (int o = 32; o > 0; o >>= 1) psum += __shfl_down(psum, o, 64);
            if (lane == 0) ((float*)sh.d.red[ph & 1])[wid] = psum;

            __syncthreads();
        }

        // ---- fused SPARSE epilogue: emd = sum over entries of u * K * v * d ----
        {
            float accA = 0.0f, accB = 0.0f;
            for (int pr = 0; pr < 2; ++pr) {
                const uint32_t* ep = pr ? rB : rA;
                const int jm = pr ? jBu : jAu;
                float a0 = 0.0f, a1 = 0.0f;
                for (int j4 = 0; j4 < jm; ++j4) {
                    uint4 e4 = ldE(ep, j4);
                    uint32_t ee[4] = { e4.x, e4.y, e4.z, e4.w };
                    #pragma unroll
                    for (int k = 0; k < 4; ++k) {
                        uint32_t e = ee[k];
                        if ((e >> 14) != 0u) {
                            float kv = __uint_as_float(e & 0xFFFFC000u);
                            float d  = -0.01f * logf(kv);
                            float t  = kv * GATHER(e, 16384);      // K * v
                            if (k & 1) a1 = fmaf(t, d, a1); else a0 = fmaf(t, d, a0);
                        }
                    }
                }
                if (pr) accB = a0 + a1; else accA = a0 + a1;
            }
            float psum = W[posA] * accA + W[posB] * accB;      // u * sum(K v d)
            #pragma unroll
            for (int o = 32; o > 0; o >>= 1) psum += __shfl_down(psum, o, 64);
            if (lane == 0) ((float*)sh.d.red[0])[wid] = psum;
            __syncthreads();
            if (tid == 0) {
                const float* rp = (const float*)sh.d.red[0];
                float t = 0.0f;
                #pragma unroll
                for (int w = 0; w < NWAVE; ++w) t += rp[w];
                atomicAdd(out, t * 0.125f);                    // mean over 8 batches
            }
        }
    }
}

extern "C" void kernel_launch(void* const* d_in, const int* in_sizes, int n_in,
                              void* d_out, int out_size, void* d_ws, size_t ws_size,
                              hipStream_t stream)
{
    const float* src = (const float*)d_in[0];
    const float* tgt = (const float*)d_in[1];
    float* out = (float*)d_out;
    uint8_t* ws = (uint8_t*)d_ws;

    void* args[] = { (void*)&src, (void*)&tgt, (void*)&ws, (void*)&out };
    hipLaunchCooperativeKernel((const void*)emd_fused_56831007261025,
                               dim3(256), dim3(TPB), args, 0, stream);
}

// Round 15
// 459.263 us; speedup vs baseline: 1.3694x; 1.3694x over previous
//
#include <hip/hip_runtime.h>
#include <stdint.h>
#include <stddef.h>

// ---------------- problem constants ----------------
#define BATCH 8
#define NPT   2048
#define NB    (BATCH*NPT)            // 16384
#define CAP   128                    // max sparse entries per row/col
#define ITERS 100
#define TPB   1024
#define NWAVE (TPB/64)
#define C50      1.9287498479639178e-22f   // expf(-50.f) == clamp floor of K
#define MUV      (1.0f/2048.0f)
#define EPS_DIVF 1e-8f
// Sparsity radius: d^2 < 0.1089 (d < 0.33). See r8/r9 analysis: dropped shell
// sums stay below the EPS_DIV clamp floor for isolated rows. The sparse
// epilogue drops far-pair transport mass bounded by ~2e-8 absolute.
#define R2THR 0.1089f

// ---------------- workspace layout (bytes), 16B-aligned ----------------
#define OFF_GMAX 0u                                   // gmax[dir][b*32+g], 2 KB used
#define OFF_CNT  4096u                                // u16 cnt[dir][b][n], 64 KB
#define OFF_PERM (OFF_CNT  + (size_t)2*NB*2)          // u16 perm[dir][b][p], 64 KB (pos -> orig)
#define OFF_IPRM (OFF_PERM + (size_t)2*NB*2)          // u16 inv [dir][b][n], 64 KB (orig -> pos)
#define OFF_SPTS (OFF_IPRM + (size_t)2*NB*2)          // float4, 256 KB
#define OFF_TPTS (OFF_SPTS + (size_t)NB*16)
#define OFF_U    (OFF_TPTS + (size_t)NB*16)           // u32 colE offset counters (kernel C)
#define OFF_V    (OFF_U + (size_t)NB*4)               // (unused)
#define OFF_ROWE (OFF_V + (size_t)NB*4)               // ELL-T4 slab (sorted rows), 8 MB
#define OFF_COLE (OFF_ROWE + (size_t)NB*CAP*4)        // 8 MB
// total 17,633,280 B — identical to the passing layout

// Entry format: value bits [31:14] (truncated; idx garbage adds zero-mean
// [0,2^-9) back), idx bits [13:2] = pre-shifted region-relative cell index.
// Gather address = single AND 0x3FFC; region base (U=0 / V=16384) folds into
// the ds_read offset immediate via phase-duplicated scan code.
__device__ __forceinline__ uint32_t pack_entry(float kv, int idx) {
    return (__float_as_uint(kv) & 0xFFFFC000u) | ((uint32_t)idx << 2);
}

// copy1 position map: bank (pi&31) mixes mid bits of i into the bank bits.
__device__ __forceinline__ uint32_t pi_map(uint32_t i) {
    return (i & 0x7E0u) | ((i ^ (i >> 5)) & 31u);
}

// ELL-T4 address of entry `ofs` of sorted-row `p` within a batch slab (dword units)
__device__ __forceinline__ size_t ellt4_addr(int ofs, int p) {
    return (size_t)(ofs >> 2) * (NPT*4) + (size_t)p * 4 + (ofs & 3);
}

// ========== kernel A: stage points + counts (both dirs) + zero slabs/counters ==========
extern "C" __global__ __launch_bounds__(TPB, 2)
void emd_count_56831007261025(const float* __restrict__ src,
                              const float* __restrict__ tgt,
                              uint8_t* __restrict__ wsb,
                              float* __restrict__ out)
{
    __shared__ float4 opts[NPT];

    uint16_t* cnt   = (uint16_t*)(wsb + OFF_CNT);
    float4*   gspts = (float4*)  (wsb + OFF_SPTS);
    float4*   gtpts = (float4*)  (wsb + OFF_TPTS);
    uint32_t* scr1  = (uint32_t*)(wsb + OFF_U);       // colE offset counters for kernel C
    uint32_t* rowE  = (uint32_t*)(wsb + OFF_ROWE);
    uint32_t* colE  = (uint32_t*)(wsb + OFF_COLE);

    const int tid  = threadIdx.x;
    const int lane = tid & 63;
    const int wid  = tid >> 6;
    const int b    = blockIdx.x >> 5;
    const int g    = blockIdx.x & 31;
    const size_t base = (size_t)b * NPT;

    if (blockIdx.x == 0 && tid == 0) *out = 0.0f;

    if (tid < 64) {
        size_t gi = base + g*64 + tid;
        gspts[gi] = make_float4(src[3*gi], src[3*gi+1], src[3*gi+2], 0.0f);
        gtpts[gi] = make_float4(tgt[3*gi], tgt[3*gi+1], tgt[3*gi+2], 0.0f);
        scr1[(size_t)blockIdx.x*64 + tid] = 0u;       // zero colE offset counters
    }

    // zero-fill this block's (b,g) slice of BOTH slabs (pad slots must read 0;
    // done HERE so kernel C's cross-block colE atomics see zeroed memory)
    {
        const size_t ebase = (size_t)b * NPT * CAP;
        for (int idx = tid; idx < 32*256; idx += TPB) {
            int j4 = idx >> 8, t = idx & 255;
            size_t a = ebase + (size_t)j4*(NPT*4) + (size_t)g*256 + t;
            rowE[a] = 0u;
            colE[a] = 0u;
        }
    }

    for (int pass = 0; pass < 2; ++pass) {
        const float* mineRaw  = pass ? tgt : src;
        const float* cloudRaw = pass ? src : tgt;

        __syncthreads();
        for (int i = tid; i < NPT; i += TPB) {
            size_t gi = base + i;
            opts[i] = make_float4(cloudRaw[3*gi], cloudRaw[3*gi+1], cloudRaw[3*gi+2], 0.0f);
        }
        __syncthreads();

        for (int r = 0; r < 4; ++r) {
            int n = g*64 + wid*4 + r;
            size_t gi = base + n;
            float4 sp = make_float4(mineRaw[3*gi], mineRaw[3*gi+1], mineRaw[3*gi+2], 0.0f);
            uint32_t c = 0;
            for (int mb = 0; mb < NPT; mb += 64) {
                float4 tp = opts[mb + lane];
                float dx = sp.x - tp.x, dy = sp.y - tp.y, dz = sp.z - tp.z;
                float d2 = dx*dx + dy*dy + dz*dz;
                c += (uint32_t)__popcll(__ballot(d2 < R2THR));
            }
            if (lane == 0) cnt[(size_t)pass*NB + gi] = (uint16_t)((c < CAP) ? c : CAP);
        }
    }
}

// ========== kernel B: counting-sort rows by count, per (dir, batch); emit inverse perm ==========
extern "C" __global__ __launch_bounds__(256, 4)
void emd_sort_56831007261025(uint8_t* __restrict__ wsb)
{
    __shared__ uint32_t hist[CAP+2];
    __shared__ uint32_t bofs[CAP+2];
    __shared__ uint16_t permL[NPT];

    const int tid = threadIdx.x;
    const int dir = blockIdx.x >> 3;
    const int b   = blockIdx.x & 7;

    const uint16_t* cnt  = (const uint16_t*)(wsb + OFF_CNT) + (size_t)dir*NB + (size_t)b*NPT;
    uint16_t*       perm = (uint16_t*)(wsb + OFF_PERM) + (size_t)dir*NB + (size_t)b*NPT;
    uint16_t*       inv  = (uint16_t*)(wsb + OFF_IPRM) + (size_t)dir*NB + (size_t)b*NPT;
    uint32_t*       gmax = (uint32_t*)(wsb + OFF_GMAX) + (size_t)dir*256 + (size_t)b*32;

    for (int i = tid; i < CAP+2; i += 256) hist[i] = 0;
    __syncthreads();
    for (int n = tid; n < NPT; n += 256) atomicAdd(&hist[cnt[n]], 1u);
    __syncthreads();
    if (tid == 0) {
        uint32_t run = 0;
        for (int i = 0; i < CAP+2; ++i) { bofs[i] = run; run += hist[i]; }
    }
    __syncthreads();
    for (int n = tid; n < NPT; n += 256) {
        uint32_t p = atomicAdd(&bofs[cnt[n]], 1u);
        permL[p] = (uint16_t)n;
    }
    __syncthreads();
    for (int p = tid; p < NPT; p += 256) {
        uint16_t o = permL[p];
        perm[p] = o;
        inv[o]  = (uint16_t)p;
    }
    if (tid < 32) gmax[tid] = cnt[permL[tid*64 + 63]];   // sorted ascending -> group max
}

// ========== kernel C: ONE symmetric dense pass builds BOTH slabs ==========
// Block owns 64 dir0-sorted rows (src points). Per hit (n, m):
//   rowE[psort(n)] entry idx = inv1[m]   (ballot-prefix slot, block-owned row)
//   colE[inv1[m]]  entry idx = psort(n)  (slot via global atomicAdd counter;
//                                         within-row order is free — kernel F
//                                         re-schedules entry order anyway)
// CAP never binds at this radius (max row count ~40 << 128).
extern "C" __global__ __launch_bounds__(TPB, 2)
void emd_build_56831007261025(uint8_t* __restrict__ wsb)
{
    __shared__ float4   opts[NPT];
    __shared__ uint16_t rows[64];
    __shared__ uint16_t invp[NPT];     // orig tgt index -> dir1 sorted pos

    const float4* gspts = (const float4*)(wsb + OFF_SPTS);
    const float4* gtpts = (const float4*)(wsb + OFF_TPTS);
    uint32_t*     rowE  = (uint32_t*)(wsb + OFF_ROWE);
    uint32_t*     colE  = (uint32_t*)(wsb + OFF_COLE);

    const int tid  = threadIdx.x;
    const int lane = tid & 63;
    const int wid  = tid >> 6;
    const int b    = blockIdx.x >> 5;
    const int g    = blockIdx.x & 31;
    const size_t base  = (size_t)b * NPT;
    const size_t ebase = (size_t)b * NPT * CAP;

    uint32_t* scr1 = (uint32_t*)(wsb + OFF_U) + base;   // per-tgt colE offset counters
    const uint16_t* permG = (const uint16_t*)(wsb + OFF_PERM) + base;              // dir0
    const uint16_t* invG  = (const uint16_t*)(wsb + OFF_IPRM) + (size_t)NB + base; // dir1

    for (int i = tid; i < NPT; i += TPB) {
        opts[i] = gtpts[base + i];
        invp[i] = invG[i];
    }
    if (tid < 64) rows[tid] = permG[g*64 + tid];
    __syncthreads();

    for (int r = 0; r < 4; ++r) {
        int psort = g*64 + wid*4 + r;              // dir0 sorted position (slab row)
        int n     = rows[wid*4 + r];               // original src row
        float4 sp = gspts[base + n];
        uint32_t c = 0;
        for (int mb = 0; mb < NPT; mb += 64) {
            int m = mb + lane;
            float4 tp = opts[m];
            float dx = sp.x - tp.x, dy = sp.y - tp.y, dz = sp.z - tp.z;
            float d2 = dx*dx + dy*dy + dz*dz;
            bool p = d2 < R2THR;
            uint64_t mask = __ballot(p);
            if (p) {
                float d  = sqrtf(d2);
                float kv = expf(-100.0f * d) - C50;
                uint32_t ofs = c + (uint32_t)__popcll(mask & ((1ull << lane) - 1ull));
                if (ofs < CAP)
                    rowE[ebase + ellt4_addr((int)ofs, psort)] = pack_entry(kv, invp[m]);
                uint32_t q  = invp[m];                       // dir1 sorted row
                uint32_t oj = atomicAdd(&scr1[m], 1u);
                if (oj < CAP)
                    colE[ebase + ellt4_addr((int)oj, (int)q)] = pack_entry(kv, psort);
            }
            c += (uint32_t)__popcll(mask);
        }
    }
}

// ========== kernel F: O(n) two-choice bank scheduler ==========
extern "C" __global__ __launch_bounds__(64)
void emd_sched_56831007261025(uint8_t* __restrict__ wsb)
{
    __shared__ uint32_t se[32*256];     // 32 KB staged slab slice
    __shared__ uint8_t  cw[64*32];      // 2 KB per-thread bank counters

    const int tid = threadIdx.x;
    const int blk = blockIdx.x;          // 512 blocks: dir | b | g
    const int g   = blk & 31;
    const int b   = (blk >> 5) & 7;
    const int dir = blk >> 8;

    const size_t ebase = (size_t)b * NPT * CAP;
    uint32_t* E = (uint32_t*)(wsb + (dir ? OFF_COLE : OFF_ROWE)) + ebase;
    const uint32_t* gmax = (const uint32_t*)(wsb + OFF_GMAX) + (size_t)dir*256 + (size_t)b*32;

    const int cm4 = ((int)gmax[g] + 3) >> 2;
    const int S   = cm4 * 4;

    for (int j4 = 0; j4 < cm4; ++j4)
        *(uint4*)&se[j4*256 + tid*4] = *(const uint4*)(E + (size_t)j4*(NPT*4) + (size_t)g*256 + (size_t)tid*4);
    __syncthreads();

    for (int s0 = tid; s0 < S; s0 += 64) {
        *(uint64_t*)(cw + tid*32 +  0) = 0ull;
        *(uint64_t*)(cw + tid*32 +  8) = 0ull;
        *(uint64_t*)(cw + tid*32 + 16) = 0ull;
        *(uint64_t*)(cw + tid*32 + 24) = 0ull;

        const int base = (s0 >> 2)*256 + (s0 & 3);
        uint64_t padmask = 0ull;
        for (int t = 0; t < 64; ++t) {
            uint32_t e = se[base + t*4];
            if ((e >> 14) == 0u) { padmask |= 1ull << t; continue; }
            uint32_t i  = (e >> 2) & 0x7FFu;
            uint32_t p1 = pi_map(i);
            uint32_t b0 = i & 31u, b1 = p1 & 31u;
            uint8_t  c0 = cw[tid*32 + b0], c1 = cw[tid*32 + b1];
            uint32_t idx;
            if (c1 < c0) { idx = 2048u + p1; cw[tid*32 + b1] = (uint8_t)(c1 + 1); }
            else         { idx = i;          cw[tid*32 + b0] = (uint8_t)(c0 + 1); }
            se[base + t*4] = (e & 0xFFFFC000u) | (idx << 2);
        }
        if (padmask) {
            uint32_t best = 0, bc = 255;
            for (uint32_t bb = 0; bb < 32; ++bb) {
                uint32_t c = cw[tid*32 + bb];
                if (c < bc) { bc = c; best = bb; }
            }
            uint32_t pw = (2048u + best) << 2;  // value bits zero -> pad marker, skipped in epilogue
            while (padmask) {
                int t = __ffsll((unsigned long long)padmask) - 1;
                padmask &= padmask - 1;
                se[base + t*4] = pw;
            }
        }
    }
    __syncthreads();

    for (int j4 = 0; j4 < cm4; ++j4)
        *(uint4*)(E + (size_t)j4*(NPT*4) + (size_t)g*256 + (size_t)tid*4) = *(const uint4*)&se[j4*256 + tid*4];
}

// ========== kernel D: 100 Sinkhorn iterations + fused sparse EMD epilogue ==========
__device__ __forceinline__ uint4 ldE(const uint32_t* ep, int j4) {
    return *(const uint4*)(ep + (size_t)j4 * (NPT*4));   // coalesced 1KB per (group, j4)
}

// Gather: byte offset = (e & 0x3FFC); region base OFS is a compile-time const.
#define GATHER(e, OFS) (*(const float*)((const uint8_t*)W + (OFS) + ((e) & 0x3FFCu)))
// component-wise accumulators: the 4 gather-FMAs of one uint4 are independent
#define FMA4C(a0, a1, a2, a3, e4, OFS) do { \
    a0 = fmaf(__uint_as_float((e4).x), GATHER((e4).x, OFS), a0); \
    a1 = fmaf(__uint_as_float((e4).y), GATHER((e4).y, OFS), a1); \
    a2 = fmaf(__uint_as_float((e4).z), GATHER((e4).z, OFS), a2); \
    a3 = fmaf(__uint_as_float((e4).w), GATHER((e4).w, OFS), a3); \
} while (0)

// full dual-group scan at compile-time region offset OFS
#define SCAN(OFS) do { \
    FMA4C(A0,A1,A2,A3, pfA0, OFS); FMA4C(A0,A1,A2,A3, pfA1, OFS); \
    FMA4C(B0,B1,B2,B3, pfB0, OFS); FMA4C(B0,B1,B2,B3, pfB1, OFS); \
    int j4 = 2; \
    for (; j4 + 1 < jmin; j4 += 2) { \
        uint4 x0 = ldE(eA, j4),   y0 = ldE(eB, j4); \
        uint4 x1 = ldE(eA, j4+1), y1 = ldE(eB, j4+1); \
        FMA4C(A0,A1,A2,A3, x0, OFS); FMA4C(B0,B1,B2,B3, y0, OFS); \
        FMA4C(A0,A1,A2,A3, x1, OFS); FMA4C(B0,B1,B2,B3, y1, OFS); \
    } \
    if (j4 < jmin) { \
        uint4 x0 = ldE(eA, j4), y0 = ldE(eB, j4); \
        FMA4C(A0,A1,A2,A3, x0, OFS); FMA4C(B0,B1,B2,B3, y0, OFS); \
        ++j4; \
    } \
    for (; j4 + 1 < jbig; j4 += 2) { \
        uint4 x0 = ldE(eL, j4), x1 = ldE(eL, j4+1); \
        FMA4C(R0,R1,R2,R3, x0, OFS); FMA4C(R4,R5,R6,R7, x1, OFS); \
    } \
    if (j4 < jbig) { uint4 x0 = ldE(eL, j4); FMA4C(R0,R1,R2,R3, x0, OFS); } \
} while (0)

extern "C" __global__ __launch_bounds__(TPB, 1)
void emd_iterate_56831007261025(uint8_t* __restrict__ wsb,
                                float* __restrict__ out)
{
    __shared__ float    W[8192];          // 32 KB: U region dwords [0..4095] (copy0, copy1),
                                          //        V region dwords [4096..8191] (byte 16384)
    __shared__ float4   red[2][NWAVE/4];  // 16 wave partials per parity, read as float4
    __shared__ uint32_t gmL[2][32];

    const int tid  = threadIdx.x;
    const int lane = tid & 63;
    const int wid  = tid >> 6;
    const int b    = blockIdx.x;
    const size_t ebase = (size_t)b * NPT * CAP;

    const uint32_t* rowE = (const uint32_t*)(wsb + OFF_ROWE) + ebase;
    const uint32_t* colE = (const uint32_t*)(wsb + OFF_COLE) + ebase;
    const uint32_t* gmax = (const uint32_t*)(wsb + OFF_GMAX);

    if (tid < 32) {
        gmL[0][tid] = gmax[(size_t)b*32 + tid];
        gmL[1][tid] = gmax[256 + (size_t)b*32 + tid];
    }
    for (int i = tid; i < 4096; i += TPB) W[4096 + i] = 1.0f;   // v0 = ones (both copies)
    __syncthreads();

    // fixed lane->sorted-row assignment: pair small group (wid) with large group (31-wid)
    const int gA = wid, gB = 31 - wid;
    const int posA = gA*64 + lane, posB = gB*64 + lane;
    const int pA1 = 2048 + (int)pi_map((uint32_t)posA);  // copy1 cells (region-relative)
    const int pB1 = 2048 + (int)pi_map((uint32_t)posB);
    const int jAu = (__builtin_amdgcn_readfirstlane((int)gmL[0][gA]) + 3) >> 2;
    const int jBu = (__builtin_amdgcn_readfirstlane((int)gmL[0][gB]) + 3) >> 2;
    const int jAv = (__builtin_amdgcn_readfirstlane((int)gmL[1][gA]) + 3) >> 2;
    const int jBv = (__builtin_amdgcn_readfirstlane((int)gmL[1][gB]) + 3) >> 2;
    const uint32_t* rA = rowE + (size_t)posA * 4;
    const uint32_t* rB = rowE + (size_t)posB * 4;
    const uint32_t* cA = colE + (size_t)posA * 4;
    const uint32_t* cB = colE + (size_t)posB * 4;

    // cross-barrier prefetch of the first 2 j4-blocks (E is static; pads contribute ~0 => safe)
    uint4 pfA0 = ldE(rA, 0), pfA1 = ldE(rA, 1);
    uint4 pfB0 = ldE(rB, 0), pfB1 = ldE(rB, 1);

    for (int ph = 0; ph < 2*ITERS; ++ph) {
        const bool up = (ph & 1) == 0;                   // u-phase reads V region, writes U
        const int jA = up ? jAu : jAv;
        const int jB = up ? jBu : jBv;
        const uint32_t* eA = up ? rA : cA;
        const uint32_t* eB = up ? rB : cB;
        const uint32_t* eL = (jA > jB) ? eA : eB;        // wave-uniform
        const int jmin = (jA < jB) ? jA : jB;
        const int jbig = (jA > jB) ? jA : jB;

        float A0=0.f,A1=0.f,A2=0.f,A3=0.f, B0=0.f,B1=0.f,B2=0.f,B3=0.f;
        float R0=0.f,R1=0.f,R2=0.f,R3=0.f, R4=0.f,R5=0.f,R6=0.f,R7=0.f;

        // phase-duplicated scan: region base folds into ds_read offset immediate
        if (up) SCAN(16384); else SCAN(0);

        float accA = (A0+A1)+(A2+A3);
        float accB = (B0+B1)+(B2+B3);
        float accR = ((R0+R1)+(R2+R3)) + ((R4+R5)+(R6+R7));
        if (jA > jB) accA += accR; else accB += accR;

        // ---- issue next-phase prefetch early (hides L2 latency under epilogue+barrier) ----
        const uint32_t* nA = up ? cA : rA;
        const uint32_t* nB = up ? cB : rB;
        pfA0 = ldE(nA, 0); pfA1 = ldE(nA, 1);
        pfB0 = ldE(nB, 0); pfB1 = ldE(nB, 1);

        // Sw off the critical path: only needed for the C50 floor term.
        // red[] read as 4x float4 (4 LDS ops, not 16).
        float Sw;
        if (ph == 0) {
            Sw = (float)NPT;                             // sum(v0) = 2048 exactly
        } else {
            const float4* rp = red[(ph - 1) & 1];
            float4 r0 = rp[0], r1 = rp[1], r2 = rp[2], r3 = rp[3];
            Sw = (((r0.x+r0.y)+(r0.z+r0.w)) + ((r1.x+r1.y)+(r1.z+r1.w)))
               + (((r2.x+r2.y)+(r2.z+r2.w)) + ((r3.x+r3.y)+(r3.z+r3.w)));
        }

        const int wrofs = up ? 0 : 4096;                 // output region (dwords)
        float valA = MUV * __builtin_amdgcn_rcpf(fmaxf(fmaf(C50, Sw, accA), EPS_DIVF));
        float valB = MUV * __builtin_amdgcn_rcpf(fmaxf(fmaf(C50, Sw, accB), EPS_DIVF));
        W[wrofs + posA] = valA;   W[wrofs + pA1] = valA;  // both copies; conflict-free
        W[wrofs + posB] = valB;   W[wrofs + pB1] = valB;

        float psum = valA + valB;
        #pragma unroll
        for (int o = 32; o > 0; o >>= 1) psum += __shfl_down(psum, o, 64);
        if (lane == 0) ((float*)red[ph & 1])[wid] = psum;

        __syncthreads();
    }

    // ---- fused SPARSE epilogue: emd = sum over entries of u * K * v * d ----
    // d recovered from the stored value: d = -ln(kv)/100. Pads skip via the
    // exact (e>>14)==0 test. Far pairs (d >= 0.33) dropped: <= ~2e-8 abs.
    {
        float accA = 0.0f, accB = 0.0f;
        for (int pr = 0; pr < 2; ++pr) {
            const uint32_t* ep = pr ? rB : rA;
            const int jm = pr ? jBu : jAu;
            float a0 = 0.0f, a1 = 0.0f;
            for (int j4 = 0; j4 < jm; ++j4) {
                uint4 e4 = ldE(ep, j4);
                uint32_t ee[4] = { e4.x, e4.y, e4.z, e4.w };
                #pragma unroll
                for (int k = 0; k < 4; ++k) {
                    uint32_t e = ee[k];
                    if ((e >> 14) != 0u) {
                        float kv = __uint_as_float(e & 0xFFFFC000u);
                        float d  = -0.01f * logf(kv);
                        float t  = kv * GATHER(e, 16384);      // K * v
                        if (k & 1) a1 = fmaf(t, d, a1); else a0 = fmaf(t, d, a0);
                    }
                }
            }
            if (pr) accB = a0 + a1; else accA = a0 + a1;
        }
        float psum = W[posA] * accA + W[posB] * accB;      // u * sum(K v d)
        #pragma unroll
        for (int o = 32; o > 0; o >>= 1) psum += __shfl_down(psum, o, 64);
        if (lane == 0) ((float*)red[0])[wid] = psum;
        __syncthreads();
        if (tid == 0) {
            const float* rp = (const float*)red[0];
            float t = 0.0f;
            #pragma unroll
            for (int w = 0; w < NWAVE; ++w) t += rp[w];
            atomicAdd(out, t * 0.125f);                    // mean over 8 batches
        }
    }
}

extern "C" void kernel_launch(void* const* d_in, const int* in_sizes, int n_in,
                              void* d_out, int out_size, void* d_ws, size_t ws_size,
                              hipStream_t stream)
{
    const float* src = (const float*)d_in[0];
    const float* tgt = (const float*)d_in[1];
    float* out = (float*)d_out;
    uint8_t* ws = (uint8_t*)d_ws;

    emd_count_56831007261025  <<<dim3(256), dim3(TPB), 0, stream>>>(src, tgt, ws, out);
    emd_sort_56831007261025   <<<dim3(16),  dim3(256), 0, stream>>>(ws);
    emd_build_56831007261025  <<<dim3(256), dim3(TPB), 0, stream>>>(ws);
    emd_sched_56831007261025  <<<dim3(512), dim3(64),  0, stream>>>(ws);
    emd_iterate_56831007261025<<<dim3(8),   dim3(TPB), 0, stream>>>(ws, out);
}